// Round 1
// baseline (35674.551 us; speedup 1.0000x reference)
//
#include <hip/hip_runtime.h>
#include <hip/hip_bf16.h>
#include <math.h>

#define B_ 4
#define L_ 301
#define D_ 768
#define DI_ 1536
#define NP_ 300
#define POS_ 150

__device__ __forceinline__ float siluf(float x) { return x / (1.f + __expf(-x)); }
__device__ __forceinline__ float softplusf(float x) { return x > 20.f ? x : log1pf(__expf(x)); }

// ---------------------------------------------------------------------------
// Generic fp32 GEMM: C[M,N] = act(A[M,K] @ W[N,K]^T + bias)
// act: 0 = none, 1 = +bias, 2 = softplus(x + bias)
// Tiles: 64x64, BK=16, 256 threads, 4x4 microtile per thread.
// ---------------------------------------------------------------------------
__global__ void gemm_bt(const float* __restrict__ A, int lda,
                        const float* __restrict__ W, int ldw,
                        const float* __restrict__ bias,
                        float* __restrict__ C, int ldc,
                        int M, int N, int K, int act) {
    __shared__ float As[16][68];
    __shared__ float Ws[16][68];
    const int tid = threadIdx.x;
    const int bm = blockIdx.y * 64;
    const int bn = blockIdx.x * 64;
    const int tx = tid & 15, ty = tid >> 4;
    float acc[4][4] = {};

    const int lk = tid & 15;       // k within tile for loads
    const int lm = tid >> 4;       // row-group base for loads

    for (int k0 = 0; k0 < K; k0 += 16) {
        const int ak = k0 + lk;
#pragma unroll
        for (int i = 0; i < 4; i++) {
            int m = bm + lm + i * 16;
            float v = 0.f;
            if (m < M && ak < K) v = A[(long)m * lda + ak];
            As[lk][lm + i * 16] = v;
        }
#pragma unroll
        for (int i = 0; i < 4; i++) {
            int n = bn + lm + i * 16;
            float v = 0.f;
            if (n < N && ak < K) v = W[(long)n * ldw + ak];
            Ws[lk][lm + i * 16] = v;
        }
        __syncthreads();
#pragma unroll
        for (int kk = 0; kk < 16; kk++) {
            float a[4], w[4];
#pragma unroll
            for (int i = 0; i < 4; i++) a[i] = As[kk][ty * 4 + i];
#pragma unroll
            for (int j = 0; j < 4; j++) w[j] = Ws[kk][tx * 4 + j];
#pragma unroll
            for (int i = 0; i < 4; i++)
#pragma unroll
                for (int j = 0; j < 4; j++) acc[i][j] += a[i] * w[j];
        }
        __syncthreads();
    }
#pragma unroll
    for (int i = 0; i < 4; i++) {
        int m = bm + ty * 4 + i;
        if (m >= M) continue;
#pragma unroll
        for (int j = 0; j < 4; j++) {
            int n = bn + tx * 4 + j;
            if (n >= N) continue;
            float v = acc[i][j];
            if (act >= 1) v += bias[n];
            if (act == 2) v = softplusf(v);
            C[(long)m * ldc + n] = v;
        }
    }
}

// ---------------------------------------------------------------------------
// Patch-embed GEMM: C[1200,768] = gather(img)[1200,12288] @ patch_w[768,12288]^T + patch_b
// A row = b*300 + gi*15 + gj ; A col k = c*4096 + p*64 + q
// ---------------------------------------------------------------------------
__global__ void gemm_patch(const float* __restrict__ img,
                           const float* __restrict__ W,
                           const float* __restrict__ bias,
                           float* __restrict__ C) {
    __shared__ float As[16][68];
    __shared__ float Ws[16][68];
    const int tid = threadIdx.x;
    const int bm = blockIdx.y * 64;
    const int bn = blockIdx.x * 64;
    const int tx = tid & 15, ty = tid >> 4;
    const int M = 1200, N = 768, K = 12288;
    float acc[4][4] = {};
    const int lk = tid & 15;
    const int lm = tid >> 4;

    for (int k0 = 0; k0 < K; k0 += 16) {
        const int ak = k0 + lk;
        const int q = ak & 63, p = (ak >> 6) & 63, c = ak >> 12;
#pragma unroll
        for (int i = 0; i < 4; i++) {
            int m = bm + lm + i * 16;
            float v = 0.f;
            if (m < M) {
                int gj = m % 15, gi = (m / 15) % 20, b = m / 300;
                v = img[(((long)(b * 3 + c) * 1280) + gi * 64 + p) * 960 + gj * 64 + q];
            }
            As[lk][lm + i * 16] = v;
        }
#pragma unroll
        for (int i = 0; i < 4; i++) {
            int n = bn + lm + i * 16;
            float v = 0.f;
            if (n < N) v = W[(long)n * K + ak];
            Ws[lk][lm + i * 16] = v;
        }
        __syncthreads();
#pragma unroll
        for (int kk = 0; kk < 16; kk++) {
            float a[4], w[4];
#pragma unroll
            for (int i = 0; i < 4; i++) a[i] = As[kk][ty * 4 + i];
#pragma unroll
            for (int j = 0; j < 4; j++) w[j] = Ws[kk][tx * 4 + j];
#pragma unroll
            for (int i = 0; i < 4; i++)
#pragma unroll
                for (int j = 0; j < 4; j++) acc[i][j] += a[i] * w[j];
        }
        __syncthreads();
    }
#pragma unroll
    for (int i = 0; i < 4; i++) {
        int m = bm + ty * 4 + i;
        if (m >= M) continue;
#pragma unroll
        for (int j = 0; j < 4; j++) {
            int n = bn + tx * 4 + j;
            if (n >= N) continue;
            C[(long)m * N + n] = acc[i][j] + bias[n];
        }
    }
}

// ---------------------------------------------------------------------------
// Assemble sequence: insert cls at POS, add pos_embed, zero res.
// ---------------------------------------------------------------------------
__global__ void assemble(const float* __restrict__ xt, const float* __restrict__ cls,
                         const float* __restrict__ pos, float* __restrict__ x,
                         float* __restrict__ res) {
    int idx = blockIdx.x * 256 + threadIdx.x;
    if (idx >= B_ * L_ * D_) return;
    int d = idx % D_;
    int l = (idx / D_) % L_;
    int b = idx / (D_ * L_);
    float v;
    if (l == POS_) {
        v = cls[d];
    } else {
        int p = (l < POS_) ? l : l - 1;
        v = xt[((long)b * NP_ + p) * D_ + d];
    }
    x[idx] = v + pos[l * D_ + d];
    res[idx] = 0.f;
}

// ---------------------------------------------------------------------------
// res += h ; hn = rms(res) * w     (block per row of 768)
// ---------------------------------------------------------------------------
__global__ void add_rms(float* __restrict__ res, const float* __restrict__ h,
                        const float* __restrict__ w, float* __restrict__ hn) {
    int row = blockIdx.x;
    float* rr = res + (long)row * D_;
    const float* hr = h + (long)row * D_;
    float v[3];
    float ss = 0.f;
#pragma unroll
    for (int i = 0; i < 3; i++) {
        int d = threadIdx.x + i * 256;
        float t = rr[d] + hr[d];
        v[i] = t;
        ss += t * t;
    }
#pragma unroll
    for (int off = 1; off < 64; off <<= 1) ss += __shfl_xor(ss, off);
    __shared__ float red[4];
    __shared__ float inv;
    if ((threadIdx.x & 63) == 0) red[threadIdx.x >> 6] = ss;
    __syncthreads();
    if (threadIdx.x == 0) {
        float s = red[0] + red[1] + red[2] + red[3];
        inv = rsqrtf(s / (float)D_ + 1e-5f);
    }
    __syncthreads();
    float iv = inv;
#pragma unroll
    for (int i = 0; i < 3; i++) {
        int d = threadIdx.x + i * 256;
        rr[d] = v[i];
        hn[(long)row * D_ + d] = v[i] * iv * w[d];
    }
}

// ---------------------------------------------------------------------------
// Depthwise causal conv (K=4) + silu. rev=1: operate on reversed sequence.
// x = xz[..., :DI] (row stride 2*DI).
// ---------------------------------------------------------------------------
__global__ void conv_silu(const float* __restrict__ xz, const float* __restrict__ w,
                          const float* __restrict__ bias, float* __restrict__ out,
                          int rev) {
    int idx = blockIdx.x * 256 + threadIdx.x;
    if (idx >= B_ * L_ * DI_) return;
    int d = idx % DI_;
    int l = (idx / DI_) % L_;
    int b = idx / (DI_ * L_);
    float acc = bias[d];
#pragma unroll
    for (int k = 0; k < 4; k++) {
        int ls = l - 3 + k;
        if (ls < 0) continue;
        int lsrc = rev ? (L_ - 1 - ls) : ls;
        acc += xz[((long)(b * L_ + lsrc)) * (2 * DI_) + d] * w[d * 4 + k];
    }
    out[idx] = siluf(acc);
}

// ---------------------------------------------------------------------------
// SSM sequential scan. 16 lanes per (b,d): lane = state n.
// rev=0: y[l] = yv ; rev=1: y[L-1-l] = 0.5*(y[L-1-l] + yv) (combine pass).
// z read from xz[..., DI:] at final-sequence position.
// ---------------------------------------------------------------------------
__global__ void ssm_scan(const float* __restrict__ xc, const float* __restrict__ dt,
                         const float* __restrict__ dbl, const float* __restrict__ xz,
                         const float* __restrict__ A_log, const float* __restrict__ Dp,
                         float* __restrict__ y, int rev) {
    int tid = threadIdx.x;
    int n = tid & 15;
    int g = tid >> 4;
    int G = blockIdx.x * 16 + g;
    int b = G / DI_;
    int d = G - b * DI_;
    float a = -__expf(A_log[d * 16 + n]);
    float Dv = Dp[d];
    float h = 0.f;
    const float* xcp = xc + (long)b * L_ * DI_ + d;
    const float* dtp = dt + (long)b * L_ * DI_ + d;
    const float* dbp = dbl + (long)b * L_ * 80;
    const float* zp = xz + (long)b * L_ * (2 * DI_) + DI_ + d;
    float* yp = y + (long)b * L_ * DI_ + d;
    for (int l = 0; l < L_; l++) {
        float dtv = dtp[(long)l * DI_];
        float xcv = xcp[(long)l * DI_];
        float bm = dbp[l * 80 + 48 + n];
        float cm = dbp[l * 80 + 64 + n];
        h = __expf(dtv * a) * h + dtv * xcv * bm;
        float c = h * cm;
        c += __shfl_xor(c, 1);
        c += __shfl_xor(c, 2);
        c += __shfl_xor(c, 4);
        c += __shfl_xor(c, 8);
        if (n == 0) {
            int lz = rev ? (L_ - 1 - l) : l;
            float zv = zp[(long)lz * (2 * DI_)];
            float yv = (c + xcv * Dv) * siluf(zv);
            if (!rev) {
                yp[(long)l * DI_] = yv;
            } else {
                long o = (long)(L_ - 1 - l) * DI_;
                yp[o] = 0.5f * (yp[o] + yv);
            }
        }
    }
}

// ---------------------------------------------------------------------------
// Final rms on the POS row only -> clsv[b, 768]
// ---------------------------------------------------------------------------
__global__ void final_rms(const float* __restrict__ res, const float* __restrict__ h,
                          const float* __restrict__ w, float* __restrict__ out) {
    int b = blockIdx.x;
    long base = ((long)b * L_ + POS_) * D_;
    float v[3];
    float ss = 0.f;
#pragma unroll
    for (int i = 0; i < 3; i++) {
        int d = threadIdx.x + i * 256;
        float t = res[base + d] + h[base + d];
        v[i] = t;
        ss += t * t;
    }
#pragma unroll
    for (int off = 1; off < 64; off <<= 1) ss += __shfl_xor(ss, off);
    __shared__ float red[4];
    __shared__ float inv;
    if ((threadIdx.x & 63) == 0) red[threadIdx.x >> 6] = ss;
    __syncthreads();
    if (threadIdx.x == 0) {
        float s = red[0] + red[1] + red[2] + red[3];
        inv = rsqrtf(s / (float)D_ + 1e-5f);
    }
    __syncthreads();
    float iv = inv;
#pragma unroll
    for (int i = 0; i < 3; i++) {
        int d = threadIdx.x + i * 256;
        out[b * D_ + d] = v[i] * iv * w[d];
    }
}

// ---------------------------------------------------------------------------
extern "C" void kernel_launch(void* const* d_in, const int* in_sizes, int n_in,
                              void* d_out, int out_size, void* d_ws, size_t ws_size,
                              hipStream_t stream) {
    const float* img = (const float*)d_in[0];
    const float* patch_w = (const float*)d_in[1];
    const float* patch_b = (const float*)d_in[2];
    const float* cls_token = (const float*)d_in[3];
    const float* pos_embed = (const float*)d_in[4];
    const float* norm_w = (const float*)d_in[5];
    const float* in_proj_w = (const float*)d_in[6];
    const float* conv_f_w = (const float*)d_in[7];
    const float* conv_f_b = (const float*)d_in[8];
    const float* xproj_f_w = (const float*)d_in[9];
    const float* dt_f_w = (const float*)d_in[10];
    const float* dt_f_b = (const float*)d_in[11];
    const float* A_f_log = (const float*)d_in[12];
    const float* D_f = (const float*)d_in[13];
    const float* conv_b_w = (const float*)d_in[14];
    const float* conv_b_b = (const float*)d_in[15];
    const float* xproj_b_w = (const float*)d_in[16];
    const float* dt_b_w = (const float*)d_in[17];
    const float* dt_b_b = (const float*)d_in[18];
    const float* A_b_log = (const float*)d_in[19];
    const float* D_b = (const float*)d_in[20];
    const float* out_proj_w = (const float*)d_in[21];
    const float* norm_f_w = (const float*)d_in[22];
    const float* head_w = (const float*)d_in[23];
    const float* head_b = (const float*)d_in[24];

    float* ws = (float*)d_ws;
    size_t off = 0;
    float* xtmp = ws + off; off += (size_t)NP_ * B_ * D_;        // 921600
    float* x    = ws + off; off += (size_t)B_ * L_ * D_;         // h stream
    float* res  = ws + off; off += (size_t)B_ * L_ * D_;
    float* hn   = ws + off; off += (size_t)B_ * L_ * D_;
    float* xz   = ws + off; off += (size_t)B_ * L_ * 2 * DI_;
    float* xcf  = ws + off; off += (size_t)B_ * L_ * DI_;
    float* xcb  = ws + off; off += (size_t)B_ * L_ * DI_;
    float* dtf  = ws + off; off += (size_t)B_ * L_ * DI_;
    float* dtb  = ws + off; off += (size_t)B_ * L_ * DI_;
    float* y    = ws + off; off += (size_t)B_ * L_ * DI_;
    float* dblf = ws + off; off += (size_t)B_ * L_ * 80;
    float* dblb = ws + off; off += (size_t)B_ * L_ * 80;
    float* clsv = ws + off; off += (size_t)B_ * D_;

    const int M = B_ * L_;  // 1204

    // --- embed ---
    gemm_patch<<<dim3(12, 19), 256, 0, stream>>>(img, patch_w, patch_b, xtmp);
    assemble<<<(B_ * L_ * D_ + 255) / 256, 256, 0, stream>>>(xtmp, cls_token, pos_embed, x, res);

    // --- layers ---
    for (int layer = 0; layer < 24; layer++) {
        const float* ipw = in_proj_w + (size_t)layer * 2 * DI_ * D_;
        const float* cfw = conv_f_w + (size_t)layer * DI_ * 4;
        const float* cfb = conv_f_b + (size_t)layer * DI_;
        const float* xfw = xproj_f_w + (size_t)layer * 80 * DI_;
        const float* dfw = dt_f_w + (size_t)layer * DI_ * 48;
        const float* dfb = dt_f_b + (size_t)layer * DI_;
        const float* afl = A_f_log + (size_t)layer * DI_ * 16;
        const float* df = D_f + (size_t)layer * DI_;
        const float* cbw = conv_b_w + (size_t)layer * DI_ * 4;
        const float* cbb = conv_b_b + (size_t)layer * DI_;
        const float* xbw = xproj_b_w + (size_t)layer * 80 * DI_;
        const float* dbw = dt_b_w + (size_t)layer * DI_ * 48;
        const float* dbb = dt_b_b + (size_t)layer * DI_;
        const float* abl = A_b_log + (size_t)layer * DI_ * 16;
        const float* db = D_b + (size_t)layer * DI_;
        const float* opw = out_proj_w + (size_t)layer * D_ * DI_;
        const float* nw = norm_w + (size_t)layer * D_;

        add_rms<<<M, 256, 0, stream>>>(res, x, nw, hn);
        gemm_bt<<<dim3(48, 19), 256, 0, stream>>>(hn, D_, ipw, D_, nullptr, xz, 2 * DI_,
                                                  M, 2 * DI_, D_, 0);
        conv_silu<<<(B_ * L_ * DI_ + 255) / 256, 256, 0, stream>>>(xz, cfw, cfb, xcf, 0);
        conv_silu<<<(B_ * L_ * DI_ + 255) / 256, 256, 0, stream>>>(xz, cbw, cbb, xcb, 1);
        gemm_bt<<<dim3(2, 19), 256, 0, stream>>>(xcf, DI_, xfw, DI_, nullptr, dblf, 80,
                                                 M, 80, DI_, 0);
        gemm_bt<<<dim3(2, 19), 256, 0, stream>>>(xcb, DI_, xbw, DI_, nullptr, dblb, 80,
                                                 M, 80, DI_, 0);
        gemm_bt<<<dim3(24, 19), 256, 0, stream>>>(dblf, 80, dfw, 48, dfb, dtf, DI_,
                                                  M, DI_, 48, 2);
        gemm_bt<<<dim3(24, 19), 256, 0, stream>>>(dblb, 80, dbw, 48, dbb, dtb, DI_,
                                                  M, DI_, 48, 2);
        ssm_scan<<<(B_ * DI_) / 16, 256, 0, stream>>>(xcf, dtf, dblf, xz, afl, df, y, 0);
        ssm_scan<<<(B_ * DI_) / 16, 256, 0, stream>>>(xcb, dtb, dblb, xz, abl, db, y, 1);
        gemm_bt<<<dim3(12, 19), 256, 0, stream>>>(y, DI_, opw, DI_, nullptr, x, D_,
                                                  M, D_, DI_, 0);
    }

    // --- head ---
    final_rms<<<B_, 256, 0, stream>>>(res, x, norm_f_w, clsv);
    gemm_bt<<<dim3(16, 1), 256, 0, stream>>>(clsv, D_, head_w, D_, head_b,
                                             (float*)d_out, 1000, B_, 1000, D_, 1);
}

// Round 2
// 25217.751 us; speedup vs baseline: 1.4147x; 1.4147x over previous
//
#include <hip/hip_runtime.h>
#include <hip/hip_bf16.h>
#include <math.h>

#define B_ 4
#define L_ 301
#define D_ 768
#define DI_ 1536
#define NP_ 300
#define POS_ 150
#define M_ 1204

typedef __bf16 bf16;
typedef __attribute__((ext_vector_type(8))) __bf16 bf16x8;
typedef __attribute__((ext_vector_type(4))) float floatx4;

__device__ __forceinline__ float siluf(float x) { return x / (1.f + __expf(-x)); }
__device__ __forceinline__ float softplusf(float x) { return x > 20.f ? x : log1pf(__expf(x)); }

// ---------------------------------------------------------------------------
// MFMA bf16 GEMM: C[M,n] = act(A[M,K]bf16 @ W[Nw,K]f32^T + bias)
// 128x128 tile, BK=32, 256 thr (4 waves, 2x2), 4x4 16x16x32 frags per wave.
// A staged via global_load_lds (bf16, 16B); W staged fp32->bf16 manually.
// Nw = valid W rows (store masked n<Nw); Kw = valid K (W zero-padded beyond).
// act: 0 none, 1 +bias, 2 softplus(x+bias). Cb: optional bf16 mirror of C.
// ---------------------------------------------------------------------------
__global__ __launch_bounds__(256) void gemm_mfma(
    const bf16* __restrict__ A, int lda,
    const float* __restrict__ W, int ldw,
    const float* __restrict__ bias,
    float* __restrict__ C, bf16* __restrict__ Cb, int ldc,
    int M, int Nw, int Kw, int Ksteps, int act)
{
    __shared__ bf16 As[128 * 32];
    __shared__ bf16 Ws[128 * 32];
    const int t = threadIdx.x;
    const int bm = blockIdx.y * 128;
    const int bn = blockIdx.x * 128;
    const int lane = t & 63;
    const int wid = t >> 6;
    const int wr = wid >> 1, wc = wid & 1;
    const int ar = t >> 2;            // tile row 0..63 for staging
    const int ac = (t & 3) * 8;       // element col 0/8/16/24

    const bool fullNK = ((Nw & 127) == 0) && ((Kw & 31) == 0);

    floatx4 acc[4][4] = {};

    for (int ks = 0; ks < Ksteps; ks++) {
        const int k0 = ks * 32;
        // ---- A staging: async global->LDS, 2 chunks of 64 rows ----
#pragma unroll
        for (int c2 = 0; c2 < 2; c2++) {
            int r = ar + c2 * 64;
            int gm = bm + r; if (gm >= M) gm = M - 1;
            const bf16* gp = A + (size_t)gm * lda + k0 + ac;
            __builtin_amdgcn_global_load_lds(
                (const __attribute__((address_space(1))) void*)gp,
                (__attribute__((address_space(3))) void*)(As + r * 32 + ac),
                16, 0, 0);
        }
        // ---- W staging: fp32 load -> bf16 -> LDS ----
#pragma unroll
        for (int c2 = 0; c2 < 2; c2++) {
            int r = ar + c2 * 64;
            int gn = bn + r;
            float vv[8];
            if (fullNK) {
                const floatx4* wp4 = (const floatx4*)(W + (size_t)gn * ldw + k0 + ac);
                floatx4 a4 = wp4[0], b4 = wp4[1];
#pragma unroll
                for (int e = 0; e < 4; e++) { vv[e] = a4[e]; vv[e + 4] = b4[e]; }
            } else {
                const float* wp = W + (size_t)gn * ldw + k0 + ac;
#pragma unroll
                for (int e = 0; e < 8; e++) {
                    int kk = k0 + ac + e;
                    vv[e] = (gn < Nw && kk < Kw) ? wp[e] : 0.f;
                }
            }
            bf16x8 pk;
#pragma unroll
            for (int e = 0; e < 8; e++) pk[e] = (bf16)vv[e];
            *(bf16x8*)(Ws + r * 32 + ac) = pk;
        }
        __syncthreads();
        // ---- compute ----
        const int ra = wr * 64 + (lane & 15);
        const int rb = wc * 64 + (lane & 15);
        const int kb = (lane >> 4) * 8;
        bf16x8 af[4], bfm[4];
#pragma unroll
        for (int i = 0; i < 4; i++)
            af[i] = *(const bf16x8*)(As + (ra + i * 16) * 32 + kb);
#pragma unroll
        for (int j = 0; j < 4; j++)
            bfm[j] = *(const bf16x8*)(Ws + (rb + j * 16) * 32 + kb);
#pragma unroll
        for (int i = 0; i < 4; i++)
#pragma unroll
            for (int j = 0; j < 4; j++)
                acc[i][j] = __builtin_amdgcn_mfma_f32_16x16x32_bf16(af[i], bfm[j], acc[i][j], 0, 0, 0);
        __syncthreads();
    }
    // ---- epilogue ----
#pragma unroll
    for (int i = 0; i < 4; i++) {
#pragma unroll
        for (int j = 0; j < 4; j++) {
            int n = bn + wc * 64 + j * 16 + (lane & 15);
            if (n >= Nw) continue;
            float bv = (act >= 1) ? bias[n] : 0.f;
#pragma unroll
            for (int r = 0; r < 4; r++) {
                int m = bm + wr * 64 + i * 16 + (lane >> 4) * 4 + r;
                if (m >= M) continue;
                float v = acc[i][j][r] + bv;
                if (act == 2) v = softplusf(v);
                C[(size_t)m * ldc + n] = v;
                if (Cb) Cb[(size_t)m * ldc + n] = (bf16)v;
            }
        }
    }
}

// ---------------------------------------------------------------------------
// Patch-embed MFMA GEMM: C[1200,768] = gather(img)[1200,12288] @ patch_w^T + b
// Same structure; A gathered from img (fp32) and converted during staging.
// row = b*300 + gi*15 + gj ; col k = c*4096 + p*64 + q
// ---------------------------------------------------------------------------
__global__ __launch_bounds__(256) void gemm_patch_mfma(
    const float* __restrict__ img, const float* __restrict__ W,
    const float* __restrict__ bias, float* __restrict__ C)
{
    __shared__ bf16 As[128 * 32];
    __shared__ bf16 Ws[128 * 32];
    const int t = threadIdx.x;
    const int bm = blockIdx.y * 128;
    const int bn = blockIdx.x * 128;
    const int lane = t & 63;
    const int wid = t >> 6;
    const int wr = wid >> 1, wc = wid & 1;
    const int ar = t >> 2;
    const int ac = (t & 3) * 8;
    const int M = 1200, K = 12288, ldw = 12288, ldc = 768;

    // precompute per-chunk img row base
    const float* abase[2];
#pragma unroll
    for (int c2 = 0; c2 < 2; c2++) {
        int gm = bm + ar + c2 * 64; if (gm >= M) gm = M - 1;
        int b = gm / 300, rem = gm % 300;
        int gi = rem / 15, gj = rem % 15;
        abase[c2] = img + ((size_t)(b * 3) * 1280 + gi * 64) * 960 + gj * 64;
    }

    floatx4 acc[4][4] = {};

    for (int ks = 0; ks < 384; ks++) {
        const int k0 = ks * 32;
        const int k = k0 + ac;
        const int q = k & 63, p = (k >> 6) & 63, c = k >> 12;
#pragma unroll
        for (int c2 = 0; c2 < 2; c2++) {
            int r = ar + c2 * 64;
            const float* ip = abase[c2] + ((size_t)c * 1280 + p) * 960 + q;
            const floatx4* ip4 = (const floatx4*)ip;
            floatx4 a4 = ip4[0], b4 = ip4[1];
            bf16x8 pk;
#pragma unroll
            for (int e = 0; e < 4; e++) { pk[e] = (bf16)a4[e]; pk[e + 4] = (bf16)b4[e]; }
            *(bf16x8*)(As + r * 32 + ac) = pk;
        }
#pragma unroll
        for (int c2 = 0; c2 < 2; c2++) {
            int r = ar + c2 * 64;
            int gn = bn + r;
            const floatx4* wp4 = (const floatx4*)(W + (size_t)gn * ldw + k);
            floatx4 a4 = wp4[0], b4 = wp4[1];
            bf16x8 pk;
#pragma unroll
            for (int e = 0; e < 4; e++) { pk[e] = (bf16)a4[e]; pk[e + 4] = (bf16)b4[e]; }
            *(bf16x8*)(Ws + r * 32 + ac) = pk;
        }
        __syncthreads();
        const int ra = wr * 64 + (lane & 15);
        const int rb = wc * 64 + (lane & 15);
        const int kb = (lane >> 4) * 8;
        bf16x8 af[4], bfm[4];
#pragma unroll
        for (int i = 0; i < 4; i++)
            af[i] = *(const bf16x8*)(As + (ra + i * 16) * 32 + kb);
#pragma unroll
        for (int j = 0; j < 4; j++)
            bfm[j] = *(const bf16x8*)(Ws + (rb + j * 16) * 32 + kb);
#pragma unroll
        for (int i = 0; i < 4; i++)
#pragma unroll
            for (int j = 0; j < 4; j++)
                acc[i][j] = __builtin_amdgcn_mfma_f32_16x16x32_bf16(af[i], bfm[j], acc[i][j], 0, 0, 0);
        __syncthreads();
    }
#pragma unroll
    for (int i = 0; i < 4; i++) {
#pragma unroll
        for (int j = 0; j < 4; j++) {
            int n = bn + wc * 64 + j * 16 + (lane & 15);
            float bv = bias[n];
#pragma unroll
            for (int r = 0; r < 4; r++) {
                int m = bm + wr * 64 + i * 16 + (lane >> 4) * 4 + r;
                if (m >= M) continue;
                C[(size_t)m * ldc + n] = acc[i][j][r] + bv;
            }
        }
    }
}

// ---------------------------------------------------------------------------
// fp32 GEMM (kept for the tiny head matmul): C = act(A @ W^T + bias)
// ---------------------------------------------------------------------------
__global__ void gemm_bt(const float* __restrict__ A, int lda,
                        const float* __restrict__ W, int ldw,
                        const float* __restrict__ bias,
                        float* __restrict__ C, int ldc,
                        int M, int N, int K, int act) {
    __shared__ float As[16][68];
    __shared__ float Ws[16][68];
    const int tid = threadIdx.x;
    const int bm = blockIdx.y * 64;
    const int bn = blockIdx.x * 64;
    const int tx = tid & 15, ty = tid >> 4;
    float acc[4][4] = {};
    const int lk = tid & 15;
    const int lm = tid >> 4;
    for (int k0 = 0; k0 < K; k0 += 16) {
        const int ak = k0 + lk;
#pragma unroll
        for (int i = 0; i < 4; i++) {
            int m = bm + lm + i * 16;
            float v = 0.f;
            if (m < M && ak < K) v = A[(long)m * lda + ak];
            As[lk][lm + i * 16] = v;
        }
#pragma unroll
        for (int i = 0; i < 4; i++) {
            int n = bn + lm + i * 16;
            float v = 0.f;
            if (n < N && ak < K) v = W[(long)n * ldw + ak];
            Ws[lk][lm + i * 16] = v;
        }
        __syncthreads();
#pragma unroll
        for (int kk = 0; kk < 16; kk++) {
            float a[4], w[4];
#pragma unroll
            for (int i = 0; i < 4; i++) a[i] = As[kk][ty * 4 + i];
#pragma unroll
            for (int j = 0; j < 4; j++) w[j] = Ws[kk][tx * 4 + j];
#pragma unroll
            for (int i = 0; i < 4; i++)
#pragma unroll
                for (int j = 0; j < 4; j++) acc[i][j] += a[i] * w[j];
        }
        __syncthreads();
    }
#pragma unroll
    for (int i = 0; i < 4; i++) {
        int m = bm + ty * 4 + i;
        if (m >= M) continue;
#pragma unroll
        for (int j = 0; j < 4; j++) {
            int n = bn + tx * 4 + j;
            if (n >= N) continue;
            float v = acc[i][j];
            if (act >= 1) v += bias[n];
            C[(long)m * ldc + n] = v;
        }
    }
}

// ---------------------------------------------------------------------------
__global__ void assemble(const float* __restrict__ xt, const float* __restrict__ cls,
                         const float* __restrict__ pos, float* __restrict__ x,
                         float* __restrict__ res) {
    int idx = blockIdx.x * 256 + threadIdx.x;
    if (idx >= B_ * L_ * D_) return;
    int d = idx % D_;
    int l = (idx / D_) % L_;
    int b = idx / (D_ * L_);
    float v;
    if (l == POS_) {
        v = cls[d];
    } else {
        int p = (l < POS_) ? l : l - 1;
        v = xt[((long)b * NP_ + p) * D_ + d];
    }
    x[idx] = v + pos[l * D_ + d];
    res[idx] = 0.f;
}

// res += h ; hn = bf16(rms(res) * w)
__global__ void add_rms(float* __restrict__ res, const float* __restrict__ h,
                        const float* __restrict__ w, bf16* __restrict__ hn) {
    int row = blockIdx.x;
    float* rr = res + (long)row * D_;
    const float* hr = h + (long)row * D_;
    float v[3];
    float ss = 0.f;
#pragma unroll
    for (int i = 0; i < 3; i++) {
        int d = threadIdx.x + i * 256;
        float t = rr[d] + hr[d];
        v[i] = t;
        ss += t * t;
    }
#pragma unroll
    for (int off = 1; off < 64; off <<= 1) ss += __shfl_xor(ss, off);
    __shared__ float red[4];
    __shared__ float inv;
    if ((threadIdx.x & 63) == 0) red[threadIdx.x >> 6] = ss;
    __syncthreads();
    if (threadIdx.x == 0) {
        float s = red[0] + red[1] + red[2] + red[3];
        inv = rsqrtf(s / (float)D_ + 1e-5f);
    }
    __syncthreads();
    float iv = inv;
#pragma unroll
    for (int i = 0; i < 3; i++) {
        int d = threadIdx.x + i * 256;
        rr[d] = v[i];
        hn[(long)row * D_ + d] = (bf16)(v[i] * iv * w[d]);
    }
}

// Depthwise causal conv (K=4) + silu -> fp32 and bf16 outputs.
__global__ void conv_silu(const float* __restrict__ xz, const float* __restrict__ w,
                          const float* __restrict__ bias, float* __restrict__ out,
                          bf16* __restrict__ outb, int rev) {
    int idx = blockIdx.x * 256 + threadIdx.x;
    if (idx >= B_ * L_ * DI_) return;
    int d = idx % DI_;
    int l = (idx / DI_) % L_;
    int b = idx / (DI_ * L_);
    float acc = bias[d];
#pragma unroll
    for (int k = 0; k < 4; k++) {
        int ls = l - 3 + k;
        if (ls < 0) continue;
        int lsrc = rev ? (L_ - 1 - ls) : ls;
        acc += xz[((long)(b * L_ + lsrc)) * (2 * DI_) + d] * w[d * 4 + k];
    }
    float v = siluf(acc);
    out[idx] = v;
    outb[idx] = (bf16)v;
}

// SSM scan. fwd: write y fp32. rev: read y fp32, write yb bf16 = 0.5*(yf+yb).
__global__ void ssm_scan(const float* __restrict__ xc, const float* __restrict__ dt,
                         const float* __restrict__ dbl, const float* __restrict__ xz,
                         const float* __restrict__ A_log, const float* __restrict__ Dp,
                         float* __restrict__ y, bf16* __restrict__ yb, int rev) {
    int tid = threadIdx.x;
    int n = tid & 15;
    int g = tid >> 4;
    int G = blockIdx.x * 16 + g;
    int b = G / DI_;
    int d = G - b * DI_;
    float a = -__expf(A_log[d * 16 + n]);
    float Dv = Dp[d];
    float h = 0.f;
    const float* xcp = xc + (long)b * L_ * DI_ + d;
    const float* dtp = dt + (long)b * L_ * DI_ + d;
    const float* dbp = dbl + (long)b * L_ * 80;
    const float* zp = xz + (long)b * L_ * (2 * DI_) + DI_ + d;
    float* yp = y + (long)b * L_ * DI_ + d;
    bf16* ybp = yb ? yb + (long)b * L_ * DI_ + d : nullptr;
    for (int l = 0; l < L_; l++) {
        float dtv = dtp[(long)l * DI_];
        float xcv = xcp[(long)l * DI_];
        float bm = dbp[l * 80 + 48 + n];
        float cm = dbp[l * 80 + 64 + n];
        h = __expf(dtv * a) * h + dtv * xcv * bm;
        float c = h * cm;
        c += __shfl_xor(c, 1);
        c += __shfl_xor(c, 2);
        c += __shfl_xor(c, 4);
        c += __shfl_xor(c, 8);
        if (n == 0) {
            int lz = rev ? (L_ - 1 - l) : l;
            float zv = zp[(long)lz * (2 * DI_)];
            float yv = (c + xcv * Dv) * siluf(zv);
            if (!rev) {
                yp[(long)l * DI_] = yv;
            } else {
                long o = (long)(L_ - 1 - l) * DI_;
                ybp[o] = (bf16)(0.5f * (yp[o] + yv));
            }
        }
    }
}

__global__ void final_rms(const float* __restrict__ res, const float* __restrict__ h,
                          const float* __restrict__ w, float* __restrict__ out) {
    int b = blockIdx.x;
    long base = ((long)b * L_ + POS_) * D_;
    float v[3];
    float ss = 0.f;
#pragma unroll
    for (int i = 0; i < 3; i++) {
        int d = threadIdx.x + i * 256;
        float t = res[base + d] + h[base + d];
        v[i] = t;
        ss += t * t;
    }
#pragma unroll
    for (int off = 1; off < 64; off <<= 1) ss += __shfl_xor(ss, off);
    __shared__ float red[4];
    __shared__ float inv;
    if ((threadIdx.x & 63) == 0) red[threadIdx.x >> 6] = ss;
    __syncthreads();
    if (threadIdx.x == 0) {
        float s = red[0] + red[1] + red[2] + red[3];
        inv = rsqrtf(s / (float)D_ + 1e-5f);
    }
    __syncthreads();
    float iv = inv;
#pragma unroll
    for (int i = 0; i < 3; i++) {
        int d = threadIdx.x + i * 256;
        out[b * D_ + d] = v[i] * iv * w[d];
    }
}

// ---------------------------------------------------------------------------
extern "C" void kernel_launch(void* const* d_in, const int* in_sizes, int n_in,
                              void* d_out, int out_size, void* d_ws, size_t ws_size,
                              hipStream_t stream) {
    const float* img = (const float*)d_in[0];
    const float* patch_w = (const float*)d_in[1];
    const float* patch_b = (const float*)d_in[2];
    const float* cls_token = (const float*)d_in[3];
    const float* pos_embed = (const float*)d_in[4];
    const float* norm_w = (const float*)d_in[5];
    const float* in_proj_w = (const float*)d_in[6];
    const float* conv_f_w = (const float*)d_in[7];
    const float* conv_f_b = (const float*)d_in[8];
    const float* xproj_f_w = (const float*)d_in[9];
    const float* dt_f_w = (const float*)d_in[10];
    const float* dt_f_b = (const float*)d_in[11];
    const float* A_f_log = (const float*)d_in[12];
    const float* D_f = (const float*)d_in[13];
    const float* conv_b_w = (const float*)d_in[14];
    const float* conv_b_b = (const float*)d_in[15];
    const float* xproj_b_w = (const float*)d_in[16];
    const float* dt_b_w = (const float*)d_in[17];
    const float* dt_b_b = (const float*)d_in[18];
    const float* A_b_log = (const float*)d_in[19];
    const float* D_b = (const float*)d_in[20];
    const float* out_proj_w = (const float*)d_in[21];
    const float* norm_f_w = (const float*)d_in[22];
    const float* head_w = (const float*)d_in[23];
    const float* head_b = (const float*)d_in[24];

    char* p8 = (char*)d_ws;
    auto alloc = [&](size_t n) { char* r = p8; p8 += (n + 255) & ~(size_t)255; return r; };
    float* x    = (float*)alloc((size_t)M_ * D_ * 4);
    float* res  = (float*)alloc((size_t)M_ * D_ * 4);
    bf16*  hnb  = (bf16*) alloc((size_t)M_ * D_ * 2);
    float* xz   = (float*)alloc((size_t)M_ * 2 * DI_ * 4);
    float* xcf  = (float*)alloc((size_t)M_ * DI_ * 4);
    float* xcb  = (float*)alloc((size_t)M_ * DI_ * 4);
    bf16*  xcfb = (bf16*) alloc((size_t)M_ * DI_ * 2);
    bf16*  xcbb = (bf16*) alloc((size_t)M_ * DI_ * 2);
    float* dtf  = (float*)alloc((size_t)M_ * DI_ * 4);
    float* dtb  = (float*)alloc((size_t)M_ * DI_ * 4);
    float* yy   = (float*)alloc((size_t)M_ * DI_ * 4);
    float* dblf = (float*)alloc((size_t)M_ * 80 * 4);
    float* dblb = (float*)alloc((size_t)M_ * 80 * 4);
    bf16*  dblfb= (bf16*) alloc((size_t)M_ * 80 * 2);
    bf16*  dblbb= (bf16*) alloc((size_t)M_ * 80 * 2);
    float* clsv = (float*)alloc((size_t)B_ * D_ * 4);
    float* xtmp = dtf;   // alias: xtmp consumed before layer 0 writes dtf
    bf16*  ybb  = xcfb;  // alias: xcfb dead after xproj_f; yb written in scan_b

    // --- embed ---
    gemm_patch_mfma<<<dim3(6, 10), 256, 0, stream>>>(img, patch_w, patch_b, xtmp);
    assemble<<<(B_ * L_ * D_ + 255) / 256, 256, 0, stream>>>(xtmp, cls_token, pos_embed, x, res);

    // --- layers ---
    for (int layer = 0; layer < 24; layer++) {
        const float* ipw = in_proj_w + (size_t)layer * 2 * DI_ * D_;
        const float* cfw = conv_f_w + (size_t)layer * DI_ * 4;
        const float* cfb = conv_f_b + (size_t)layer * DI_;
        const float* xfw = xproj_f_w + (size_t)layer * 80 * DI_;
        const float* dfw = dt_f_w + (size_t)layer * DI_ * 48;
        const float* dfb = dt_f_b + (size_t)layer * DI_;
        const float* afl = A_f_log + (size_t)layer * DI_ * 16;
        const float* df = D_f + (size_t)layer * DI_;
        const float* cbw = conv_b_w + (size_t)layer * DI_ * 4;
        const float* cbb = conv_b_b + (size_t)layer * DI_;
        const float* xbw = xproj_b_w + (size_t)layer * 80 * DI_;
        const float* dbw = dt_b_w + (size_t)layer * DI_ * 48;
        const float* dbb = dt_b_b + (size_t)layer * DI_;
        const float* abl = A_b_log + (size_t)layer * DI_ * 16;
        const float* db = D_b + (size_t)layer * DI_;
        const float* opw = out_proj_w + (size_t)layer * D_ * DI_;
        const float* nw = norm_w + (size_t)layer * D_;

        add_rms<<<M_, 256, 0, stream>>>(res, x, nw, hnb);
        gemm_mfma<<<dim3(24, 10), 256, 0, stream>>>(hnb, D_, ipw, D_, nullptr,
                                                    xz, nullptr, 2 * DI_,
                                                    M_, 2 * DI_, D_, 24, 0);
        conv_silu<<<(B_ * L_ * DI_ + 255) / 256, 256, 0, stream>>>(xz, cfw, cfb, xcf, xcfb, 0);
        conv_silu<<<(B_ * L_ * DI_ + 255) / 256, 256, 0, stream>>>(xz, cbw, cbb, xcb, xcbb, 1);
        gemm_mfma<<<dim3(1, 10), 256, 0, stream>>>(xcfb, DI_, xfw, DI_, nullptr,
                                                   dblf, dblfb, 80,
                                                   M_, 80, DI_, 48, 0);
        gemm_mfma<<<dim3(1, 10), 256, 0, stream>>>(xcbb, DI_, xbw, DI_, nullptr,
                                                   dblb, dblbb, 80,
                                                   M_, 80, DI_, 48, 0);
        gemm_mfma<<<dim3(12, 10), 256, 0, stream>>>(dblfb, 80, dfw, 48, dfb,
                                                    dtf, nullptr, DI_,
                                                    M_, DI_, 48, 2, 2);
        gemm_mfma<<<dim3(12, 10), 256, 0, stream>>>(dblbb, 80, dbw, 48, dbb,
                                                    dtb, nullptr, DI_,
                                                    M_, DI_, 48, 2, 2);
        ssm_scan<<<(B_ * DI_) / 16, 256, 0, stream>>>(xcf, dtf, dblf, xz, afl, df, yy, nullptr, 0);
        ssm_scan<<<(B_ * DI_) / 16, 256, 0, stream>>>(xcb, dtb, dblb, xz, abl, db, yy, ybb, 1);
        gemm_mfma<<<dim3(6, 10), 256, 0, stream>>>(ybb, DI_, opw, DI_, nullptr,
                                                   x, nullptr, D_,
                                                   M_, D_, DI_, 48, 0);
    }

    // --- head ---
    final_rms<<<B_, 256, 0, stream>>>(res, x, norm_f_w, clsv);
    gemm_bt<<<dim3(16, 1), 256, 0, stream>>>(clsv, D_, head_w, D_, head_b,
                                             (float*)d_out, 1000, B_, 1000, D_, 1);
}

// Round 3
// 10498.508 us; speedup vs baseline: 3.3981x; 2.4020x over previous
//
#include <hip/hip_runtime.h>
#include <hip/hip_bf16.h>
#include <math.h>

#define B_ 4
#define L_ 301
#define D_ 768
#define DI_ 1536
#define NP_ 300
#define POS_ 150
#define M_ 1204
#define SCHUNK 64

typedef __bf16 bf16;
typedef __attribute__((ext_vector_type(8))) __bf16 bf16x8;
typedef __attribute__((ext_vector_type(4))) float floatx4;

__device__ __forceinline__ float siluf(float x) { return x / (1.f + __expf(-x)); }
__device__ __forceinline__ float softplusf(float x) { return x > 20.f ? x : log1pf(__expf(x)); }

// ---------------------------------------------------------------------------
// MFMA bf16 GEMM, z-batched (blockIdx.z selects operand set 0/1):
// C[M,Nw] = act(A[M,K]bf16 @ W[Nw,K]f32^T + bias)
// 128x128 tile, BK=32, 256 thr (4 waves 2x2), 4x4 16x16x32 frags/wave.
// ---------------------------------------------------------------------------
__global__ __launch_bounds__(256) void gemm_mfma(
    const bf16* __restrict__ A0, const bf16* __restrict__ A1, int lda,
    const float* __restrict__ W0, const float* __restrict__ W1, int ldw,
    const float* __restrict__ bias0, const float* __restrict__ bias1,
    float* __restrict__ C0, float* __restrict__ C1,
    bf16* __restrict__ Cb0, bf16* __restrict__ Cb1, int ldc,
    int M, int Nw, int Kw, int Ksteps, int act)
{
    const int zz = blockIdx.z;
    const bf16* A = zz ? A1 : A0;
    const float* W = zz ? W1 : W0;
    const float* bias = zz ? bias1 : bias0;
    float* C = zz ? C1 : C0;
    bf16* Cb = zz ? Cb1 : Cb0;

    __shared__ bf16 As[128 * 32];
    __shared__ bf16 Ws[128 * 32];
    const int t = threadIdx.x;
    const int bm = blockIdx.y * 128;
    const int bn = blockIdx.x * 128;
    const int lane = t & 63;
    const int wid = t >> 6;
    const int wr = wid >> 1, wc = wid & 1;
    const int ar = t >> 2;
    const int ac = (t & 3) * 8;

    const bool fullNK = ((Nw & 127) == 0) && ((Kw & 31) == 0);

    floatx4 acc[4][4] = {};

    for (int ks = 0; ks < Ksteps; ks++) {
        const int k0 = ks * 32;
#pragma unroll
        for (int c2 = 0; c2 < 2; c2++) {
            int r = ar + c2 * 64;
            int gm = bm + r; if (gm >= M) gm = M - 1;
            const bf16* gp = A + (size_t)gm * lda + k0 + ac;
            __builtin_amdgcn_global_load_lds(
                (const __attribute__((address_space(1))) void*)gp,
                (__attribute__((address_space(3))) void*)(As + r * 32 + ac),
                16, 0, 0);
        }
#pragma unroll
        for (int c2 = 0; c2 < 2; c2++) {
            int r = ar + c2 * 64;
            int gn = bn + r;
            float vv[8];
            if (fullNK) {
                const floatx4* wp4 = (const floatx4*)(W + (size_t)gn * ldw + k0 + ac);
                floatx4 a4 = wp4[0], b4 = wp4[1];
#pragma unroll
                for (int e = 0; e < 4; e++) { vv[e] = a4[e]; vv[e + 4] = b4[e]; }
            } else {
                const float* wp = W + (size_t)gn * ldw + k0 + ac;
#pragma unroll
                for (int e = 0; e < 8; e++) {
                    int kk = k0 + ac + e;
                    vv[e] = (gn < Nw && kk < Kw) ? wp[e] : 0.f;
                }
            }
            bf16x8 pk;
#pragma unroll
            for (int e = 0; e < 8; e++) pk[e] = (bf16)vv[e];
            *(bf16x8*)(Ws + r * 32 + ac) = pk;
        }
        __syncthreads();
        const int ra = wr * 64 + (lane & 15);
        const int rb = wc * 64 + (lane & 15);
        const int kb = (lane >> 4) * 8;
        bf16x8 af[4], bfm[4];
#pragma unroll
        for (int i = 0; i < 4; i++)
            af[i] = *(const bf16x8*)(As + (ra + i * 16) * 32 + kb);
#pragma unroll
        for (int j = 0; j < 4; j++)
            bfm[j] = *(const bf16x8*)(Ws + (rb + j * 16) * 32 + kb);
#pragma unroll
        for (int i = 0; i < 4; i++)
#pragma unroll
            for (int j = 0; j < 4; j++)
                acc[i][j] = __builtin_amdgcn_mfma_f32_16x16x32_bf16(af[i], bfm[j], acc[i][j], 0, 0, 0);
        __syncthreads();
    }
#pragma unroll
    for (int i = 0; i < 4; i++) {
#pragma unroll
        for (int j = 0; j < 4; j++) {
            int n = bn + wc * 64 + j * 16 + (lane & 15);
            if (n >= Nw) continue;
            float bv = (act >= 1) ? bias[n] : 0.f;
#pragma unroll
            for (int r = 0; r < 4; r++) {
                int m = bm + wr * 64 + i * 16 + (lane >> 4) * 4 + r;
                if (m >= M) continue;
                float v = acc[i][j][r] + bv;
                if (act == 2) v = softplusf(v);
                C[(size_t)m * ldc + n] = v;
                if (Cb) Cb[(size_t)m * ldc + n] = (bf16)v;
            }
        }
    }
}

// ---------------------------------------------------------------------------
// out_proj GEMM: A = bf16(0.5*(Af+Ab)) merged during staging. fullNK assumed.
// ---------------------------------------------------------------------------
__global__ __launch_bounds__(256) void gemm_mfma_avg(
    const bf16* __restrict__ Af, const bf16* __restrict__ Ab, int lda,
    const float* __restrict__ W, int ldw,
    float* __restrict__ C, int ldc,
    int M, int Nw, int Kw, int Ksteps)
{
    __shared__ bf16 As[128 * 32];
    __shared__ bf16 Ws[128 * 32];
    const int t = threadIdx.x;
    const int bm = blockIdx.y * 128;
    const int bn = blockIdx.x * 128;
    const int lane = t & 63;
    const int wid = t >> 6;
    const int wr = wid >> 1, wc = wid & 1;
    const int ar = t >> 2;
    const int ac = (t & 3) * 8;

    floatx4 acc[4][4] = {};

    for (int ks = 0; ks < Ksteps; ks++) {
        const int k0 = ks * 32;
#pragma unroll
        for (int c2 = 0; c2 < 2; c2++) {
            int r = ar + c2 * 64;
            int gm = bm + r; if (gm >= M) gm = M - 1;
            bf16x8 a8 = *(const bf16x8*)(Af + (size_t)gm * lda + k0 + ac);
            bf16x8 b8 = *(const bf16x8*)(Ab + (size_t)gm * lda + k0 + ac);
            bf16x8 pk;
#pragma unroll
            for (int e = 0; e < 8; e++)
                pk[e] = (bf16)(0.5f * ((float)a8[e] + (float)b8[e]));
            *(bf16x8*)(As + r * 32 + ac) = pk;
        }
#pragma unroll
        for (int c2 = 0; c2 < 2; c2++) {
            int r = ar + c2 * 64;
            int gn = bn + r;
            const floatx4* wp4 = (const floatx4*)(W + (size_t)gn * ldw + k0 + ac);
            floatx4 a4 = wp4[0], b4 = wp4[1];
            bf16x8 pk;
#pragma unroll
            for (int e = 0; e < 4; e++) { pk[e] = (bf16)a4[e]; pk[e + 4] = (bf16)b4[e]; }
            *(bf16x8*)(Ws + r * 32 + ac) = pk;
        }
        __syncthreads();
        const int ra = wr * 64 + (lane & 15);
        const int rb = wc * 64 + (lane & 15);
        const int kb = (lane >> 4) * 8;
        bf16x8 af[4], bfm[4];
#pragma unroll
        for (int i = 0; i < 4; i++)
            af[i] = *(const bf16x8*)(As + (ra + i * 16) * 32 + kb);
#pragma unroll
        for (int j = 0; j < 4; j++)
            bfm[j] = *(const bf16x8*)(Ws + (rb + j * 16) * 32 + kb);
#pragma unroll
        for (int i = 0; i < 4; i++)
#pragma unroll
            for (int j = 0; j < 4; j++)
                acc[i][j] = __builtin_amdgcn_mfma_f32_16x16x32_bf16(af[i], bfm[j], acc[i][j], 0, 0, 0);
        __syncthreads();
    }
#pragma unroll
    for (int i = 0; i < 4; i++) {
#pragma unroll
        for (int j = 0; j < 4; j++) {
            int n = bn + wc * 64 + j * 16 + (lane & 15);
            if (n >= Nw) continue;
#pragma unroll
            for (int r = 0; r < 4; r++) {
                int m = bm + wr * 64 + i * 16 + (lane >> 4) * 4 + r;
                if (m >= M) continue;
                C[(size_t)m * ldc + n] = acc[i][j][r];
            }
        }
    }
}

// ---------------------------------------------------------------------------
// Patch-embed MFMA GEMM (unchanged from round 2).
// ---------------------------------------------------------------------------
__global__ __launch_bounds__(256) void gemm_patch_mfma(
    const float* __restrict__ img, const float* __restrict__ W,
    const float* __restrict__ bias, float* __restrict__ C)
{
    __shared__ bf16 As[128 * 32];
    __shared__ bf16 Ws[128 * 32];
    const int t = threadIdx.x;
    const int bm = blockIdx.y * 128;
    const int bn = blockIdx.x * 128;
    const int lane = t & 63;
    const int wid = t >> 6;
    const int wr = wid >> 1, wc = wid & 1;
    const int ar = t >> 2;
    const int ac = (t & 3) * 8;
    const int M = 1200, K = 12288, ldw = 12288, ldc = 768;

    const float* abase[2];
#pragma unroll
    for (int c2 = 0; c2 < 2; c2++) {
        int gm = bm + ar + c2 * 64; if (gm >= M) gm = M - 1;
        int b = gm / 300, rem = gm % 300;
        int gi = rem / 15, gj = rem % 15;
        abase[c2] = img + ((size_t)(b * 3) * 1280 + gi * 64) * 960 + gj * 64;
    }

    floatx4 acc[4][4] = {};

    for (int ks = 0; ks < 384; ks++) {
        const int k0 = ks * 32;
        const int k = k0 + ac;
        const int q = k & 63, p = (k >> 6) & 63, c = k >> 12;
#pragma unroll
        for (int c2 = 0; c2 < 2; c2++) {
            int r = ar + c2 * 64;
            const float* ip = abase[c2] + ((size_t)c * 1280 + p) * 960 + q;
            const floatx4* ip4 = (const floatx4*)ip;
            floatx4 a4 = ip4[0], b4 = ip4[1];
            bf16x8 pk;
#pragma unroll
            for (int e = 0; e < 4; e++) { pk[e] = (bf16)a4[e]; pk[e + 4] = (bf16)b4[e]; }
            *(bf16x8*)(As + r * 32 + ac) = pk;
        }
#pragma unroll
        for (int c2 = 0; c2 < 2; c2++) {
            int r = ar + c2 * 64;
            int gn = bn + r;
            const floatx4* wp4 = (const floatx4*)(W + (size_t)gn * ldw + k);
            floatx4 a4 = wp4[0], b4 = wp4[1];
            bf16x8 pk;
#pragma unroll
            for (int e = 0; e < 4; e++) { pk[e] = (bf16)a4[e]; pk[e + 4] = (bf16)b4[e]; }
            *(bf16x8*)(Ws + r * 32 + ac) = pk;
        }
        __syncthreads();
        const int ra = wr * 64 + (lane & 15);
        const int rb = wc * 64 + (lane & 15);
        const int kb = (lane >> 4) * 8;
        bf16x8 af[4], bfm[4];
#pragma unroll
        for (int i = 0; i < 4; i++)
            af[i] = *(const bf16x8*)(As + (ra + i * 16) * 32 + kb);
#pragma unroll
        for (int j = 0; j < 4; j++)
            bfm[j] = *(const bf16x8*)(Ws + (rb + j * 16) * 32 + kb);
#pragma unroll
        for (int i = 0; i < 4; i++)
#pragma unroll
            for (int j = 0; j < 4; j++)
                acc[i][j] = __builtin_amdgcn_mfma_f32_16x16x32_bf16(af[i], bfm[j], acc[i][j], 0, 0, 0);
        __syncthreads();
    }
#pragma unroll
    for (int i = 0; i < 4; i++) {
#pragma unroll
        for (int j = 0; j < 4; j++) {
            int n = bn + wc * 64 + j * 16 + (lane & 15);
            float bv = bias[n];
#pragma unroll
            for (int r = 0; r < 4; r++) {
                int m = bm + wr * 64 + i * 16 + (lane >> 4) * 4 + r;
                if (m >= M) continue;
                C[(size_t)m * ldc + n] = acc[i][j][r] + bv;
            }
        }
    }
}

// ---------------------------------------------------------------------------
// fp32 GEMM for the tiny head matmul.
// ---------------------------------------------------------------------------
__global__ void gemm_bt(const float* __restrict__ A, int lda,
                        const float* __restrict__ W, int ldw,
                        const float* __restrict__ bias,
                        float* __restrict__ C, int ldc,
                        int M, int N, int K, int act) {
    __shared__ float As[16][68];
    __shared__ float Ws[16][68];
    const int tid = threadIdx.x;
    const int bm = blockIdx.y * 64;
    const int bn = blockIdx.x * 64;
    const int tx = tid & 15, ty = tid >> 4;
    float acc[4][4] = {};
    const int lk = tid & 15;
    const int lm = tid >> 4;
    for (int k0 = 0; k0 < K; k0 += 16) {
        const int ak = k0 + lk;
#pragma unroll
        for (int i = 0; i < 4; i++) {
            int m = bm + lm + i * 16;
            float v = 0.f;
            if (m < M && ak < K) v = A[(long)m * lda + ak];
            As[lk][lm + i * 16] = v;
        }
#pragma unroll
        for (int i = 0; i < 4; i++) {
            int n = bn + lm + i * 16;
            float v = 0.f;
            if (n < N && ak < K) v = W[(long)n * ldw + ak];
            Ws[lk][lm + i * 16] = v;
        }
        __syncthreads();
#pragma unroll
        for (int kk = 0; kk < 16; kk++) {
            float a[4], w[4];
#pragma unroll
            for (int i = 0; i < 4; i++) a[i] = As[kk][ty * 4 + i];
#pragma unroll
            for (int j = 0; j < 4; j++) w[j] = Ws[kk][tx * 4 + j];
#pragma unroll
            for (int i = 0; i < 4; i++)
#pragma unroll
                for (int j = 0; j < 4; j++) acc[i][j] += a[i] * w[j];
        }
        __syncthreads();
    }
#pragma unroll
    for (int i = 0; i < 4; i++) {
        int m = bm + ty * 4 + i;
        if (m >= M) continue;
#pragma unroll
        for (int j = 0; j < 4; j++) {
            int n = bn + tx * 4 + j;
            if (n >= N) continue;
            float v = acc[i][j];
            if (act >= 1) v += bias[n];
            C[(long)m * ldc + n] = v;
        }
    }
}

// ---------------------------------------------------------------------------
__global__ void assemble(const float* __restrict__ xt, const float* __restrict__ cls,
                         const float* __restrict__ pos, float* __restrict__ x,
                         float* __restrict__ res) {
    int idx = blockIdx.x * 256 + threadIdx.x;
    if (idx >= B_ * L_ * D_) return;
    int d = idx % D_;
    int l = (idx / D_) % L_;
    int b = idx / (D_ * L_);
    float v;
    if (l == POS_) {
        v = cls[d];
    } else {
        int p = (l < POS_) ? l : l - 1;
        v = xt[((long)b * NP_ + p) * D_ + d];
    }
    x[idx] = v + pos[l * D_ + d];
    res[idx] = 0.f;
}

// res += h ; hn = bf16(rms(res) * w)
__global__ void add_rms(float* __restrict__ res, const float* __restrict__ h,
                        const float* __restrict__ w, bf16* __restrict__ hn) {
    int row = blockIdx.x;
    float* rr = res + (long)row * D_;
    const float* hr = h + (long)row * D_;
    float v[3];
    float ss = 0.f;
#pragma unroll
    for (int i = 0; i < 3; i++) {
        int d = threadIdx.x + i * 256;
        float t = rr[d] + hr[d];
        v[i] = t;
        ss += t * t;
    }
#pragma unroll
    for (int off = 1; off < 64; off <<= 1) ss += __shfl_xor(ss, off);
    __shared__ float red[4];
    __shared__ float inv;
    if ((threadIdx.x & 63) == 0) red[threadIdx.x >> 6] = ss;
    __syncthreads();
    if (threadIdx.x == 0) {
        float s = red[0] + red[1] + red[2] + red[3];
        inv = rsqrtf(s / (float)D_ + 1e-5f);
    }
    __syncthreads();
    float iv = inv;
#pragma unroll
    for (int i = 0; i < 3; i++) {
        int d = threadIdx.x + i * 256;
        rr[d] = v[i];
        hn[(long)row * D_ + d] = (bf16)(v[i] * iv * w[d]);
    }
}

// Depthwise causal conv (K=4) + silu, both directions in one dispatch.
__global__ void conv_silu2(const float* __restrict__ xz,
                           const float* __restrict__ wf, const float* __restrict__ bf_,
                           const float* __restrict__ wb, const float* __restrict__ bb_,
                           float* __restrict__ of, bf16* __restrict__ ofb,
                           float* __restrict__ ob, bf16* __restrict__ obb) {
    int idx = blockIdx.x * 256 + threadIdx.x;
    if (idx >= B_ * L_ * DI_) return;
    const int rev = blockIdx.y;
    const float* w = rev ? wb : wf;
    const float* bias = rev ? bb_ : bf_;
    float* out = rev ? ob : of;
    bf16* outb = rev ? obb : ofb;
    int d = idx % DI_;
    int l = (idx / DI_) % L_;
    int b = idx / (DI_ * L_);
    float acc = bias[d];
#pragma unroll
    for (int k = 0; k < 4; k++) {
        int ls = l - 3 + k;
        if (ls < 0) continue;
        int lsrc = rev ? (L_ - 1 - ls) : ls;
        acc += xz[((long)(b * L_ + lsrc)) * (2 * DI_) + d] * w[d * 4 + k];
    }
    float v = siluf(acc);
    out[idx] = v;
    outb[idx] = (bf16)v;
}

// ---------------------------------------------------------------------------
// LDS-staged chunked SSM scan, fwd+bwd fused (blockIdx.y = direction).
// Block = 16 (b,d) groups x 16 state-lanes. Stages SCHUNK timesteps of
// dt/xc/z/B/C into LDS (coalesced), runs the recurrence out of LDS,
// writes y chunk coalesced as bf16 (bwd written at reversed positions).
// ---------------------------------------------------------------------------
__global__ __launch_bounds__(256) void ssm_scan2(
    const float* __restrict__ xcF, const float* __restrict__ dtF, const float* __restrict__ dblF,
    const float* __restrict__ xcB, const float* __restrict__ dtB, const float* __restrict__ dblB,
    const float* __restrict__ xz,
    const float* __restrict__ AF, const float* __restrict__ DF,
    const float* __restrict__ AB, const float* __restrict__ DB,
    bf16* __restrict__ yF, bf16* __restrict__ yB)
{
    const int rev = blockIdx.y;
    const float* xc = rev ? xcB : xcF;
    const float* dt = rev ? dtB : dtF;
    const float* dbl = rev ? dblB : dblF;
    const float* Alog = rev ? AB : AF;
    const float* Dp = rev ? DB : DF;
    bf16* yout = rev ? yB : yF;

    const int t = threadIdx.x;
    const int n = t & 15;
    const int g = t >> 4;
    const int gb = blockIdx.x;               // 0..383
    const int b = gb / (DI_ / 16);
    const int d0 = (gb % (DI_ / 16)) * 16;
    const int d = d0 + g;

    __shared__ float dt_s[SCHUNK][16];
    __shared__ float xc_s[SCHUNK][16];
    __shared__ float z_s[SCHUNK][16];
    __shared__ float bm_s[SCHUNK][16];
    __shared__ float cm_s[SCHUNK][16];
    __shared__ float y_s[SCHUNK][16];

    const float a = -__expf(Alog[(size_t)d * 16 + n]);
    const float Dv = Dp[d];
    float h = 0.f;
    const size_t rowbase = (size_t)b * L_;

    for (int c0 = 0; c0 < L_; c0 += SCHUNK) {
        const int Tc = min(SCHUNK, L_ - c0);
        // ---- stage chunk (coalesced) ----
        for (int i = t; i < Tc * 16; i += 256) {
            int ll = i >> 4, dd = i & 15;
            int l = c0 + ll;
            size_t r = (rowbase + l) * DI_ + d0 + dd;
            dt_s[ll][dd] = dt[r];
            xc_s[ll][dd] = xc[r];
            int lz = rev ? (L_ - 1 - l) : l;
            z_s[ll][dd] = xz[(rowbase + lz) * (2 * DI_) + DI_ + d0 + dd];
            bm_s[ll][dd] = dbl[(rowbase + l) * 80 + 48 + dd];
            cm_s[ll][dd] = dbl[(rowbase + l) * 80 + 64 + dd];
        }
        __syncthreads();
        // ---- recurrence from LDS ----
#pragma unroll 4
        for (int ll = 0; ll < Tc; ll++) {
            float dtv = dt_s[ll][g];
            float xcv = xc_s[ll][g];
            float bm = bm_s[ll][n];
            float cm = cm_s[ll][n];
            h = __expf(dtv * a) * h + dtv * xcv * bm;
            float cc = h * cm;
            cc += __shfl_xor(cc, 1);
            cc += __shfl_xor(cc, 2);
            cc += __shfl_xor(cc, 4);
            cc += __shfl_xor(cc, 8);
            if (n == 0) {
                float yv = (cc + xcv * Dv) * siluf(z_s[ll][g]);
                y_s[ll][g] = yv;
            }
        }
        __syncthreads();
        // ---- writeout (coalesced, bf16) ----
        for (int i = t; i < Tc * 16; i += 256) {
            int ll = i >> 4, dd = i & 15;
            int l = c0 + ll;
            int lo = rev ? (L_ - 1 - l) : l;
            yout[(rowbase + lo) * DI_ + d0 + dd] = (bf16)y_s[ll][dd];
        }
        __syncthreads();
    }
}

__global__ void final_rms(const float* __restrict__ res, const float* __restrict__ h,
                          const float* __restrict__ w, float* __restrict__ out) {
    int b = blockIdx.x;
    long base = ((long)b * L_ + POS_) * D_;
    float v[3];
    float ss = 0.f;
#pragma unroll
    for (int i = 0; i < 3; i++) {
        int d = threadIdx.x + i * 256;
        float t = res[base + d] + h[base + d];
        v[i] = t;
        ss += t * t;
    }
#pragma unroll
    for (int off = 1; off < 64; off <<= 1) ss += __shfl_xor(ss, off);
    __shared__ float red[4];
    __shared__ float inv;
    if ((threadIdx.x & 63) == 0) red[threadIdx.x >> 6] = ss;
    __syncthreads();
    if (threadIdx.x == 0) {
        float s = red[0] + red[1] + red[2] + red[3];
        inv = rsqrtf(s / (float)D_ + 1e-5f);
    }
    __syncthreads();
    float iv = inv;
#pragma unroll
    for (int i = 0; i < 3; i++) {
        int d = threadIdx.x + i * 256;
        out[b * D_ + d] = v[i] * iv * w[d];
    }
}

// ---------------------------------------------------------------------------
extern "C" void kernel_launch(void* const* d_in, const int* in_sizes, int n_in,
                              void* d_out, int out_size, void* d_ws, size_t ws_size,
                              hipStream_t stream) {
    const float* img = (const float*)d_in[0];
    const float* patch_w = (const float*)d_in[1];
    const float* patch_b = (const float*)d_in[2];
    const float* cls_token = (const float*)d_in[3];
    const float* pos_embed = (const float*)d_in[4];
    const float* norm_w = (const float*)d_in[5];
    const float* in_proj_w = (const float*)d_in[6];
    const float* conv_f_w = (const float*)d_in[7];
    const float* conv_f_b = (const float*)d_in[8];
    const float* xproj_f_w = (const float*)d_in[9];
    const float* dt_f_w = (const float*)d_in[10];
    const float* dt_f_b = (const float*)d_in[11];
    const float* A_f_log = (const float*)d_in[12];
    const float* D_f = (const float*)d_in[13];
    const float* conv_b_w = (const float*)d_in[14];
    const float* conv_b_b = (const float*)d_in[15];
    const float* xproj_b_w = (const float*)d_in[16];
    const float* dt_b_w = (const float*)d_in[17];
    const float* dt_b_b = (const float*)d_in[18];
    const float* A_b_log = (const float*)d_in[19];
    const float* D_b = (const float*)d_in[20];
    const float* out_proj_w = (const float*)d_in[21];
    const float* norm_f_w = (const float*)d_in[22];
    const float* head_w = (const float*)d_in[23];
    const float* head_b = (const float*)d_in[24];

    char* p8 = (char*)d_ws;
    auto alloc = [&](size_t nb) { char* r = p8; p8 += (nb + 255) & ~(size_t)255; return r; };
    float* x    = (float*)alloc((size_t)M_ * D_ * 4);
    float* res  = (float*)alloc((size_t)M_ * D_ * 4);
    bf16*  hnb  = (bf16*) alloc((size_t)M_ * D_ * 2);
    float* xz   = (float*)alloc((size_t)M_ * 2 * DI_ * 4);
    float* xcf  = (float*)alloc((size_t)M_ * DI_ * 4);
    float* xcb  = (float*)alloc((size_t)M_ * DI_ * 4);
    bf16*  xcfb = (bf16*) alloc((size_t)M_ * DI_ * 2);
    bf16*  xcbb = (bf16*) alloc((size_t)M_ * DI_ * 2);
    float* dtf  = (float*)alloc((size_t)M_ * DI_ * 4);
    float* dtb  = (float*)alloc((size_t)M_ * DI_ * 4);
    bf16*  yfb  = (bf16*) alloc((size_t)M_ * DI_ * 2);
    bf16*  ybb  = (bf16*) alloc((size_t)M_ * DI_ * 2);
    float* dblf = (float*)alloc((size_t)M_ * 80 * 4);
    float* dblb = (float*)alloc((size_t)M_ * 80 * 4);
    bf16*  dblfb= (bf16*) alloc((size_t)M_ * 80 * 2);
    bf16*  dblbb= (bf16*) alloc((size_t)M_ * 80 * 2);
    float* clsv = (float*)alloc((size_t)B_ * D_ * 4);
    float* xtmp = dtf;   // alias: xtmp consumed (assemble) before layer 0 writes dtf

    // --- embed ---
    gemm_patch_mfma<<<dim3(6, 10), 256, 0, stream>>>(img, patch_w, patch_b, xtmp);
    assemble<<<(B_ * L_ * D_ + 255) / 256, 256, 0, stream>>>(xtmp, cls_token, pos_embed, x, res);

    // --- layers ---
    for (int layer = 0; layer < 24; layer++) {
        const float* ipw = in_proj_w + (size_t)layer * 2 * DI_ * D_;
        const float* cfw = conv_f_w + (size_t)layer * DI_ * 4;
        const float* cfb = conv_f_b + (size_t)layer * DI_;
        const float* xfw = xproj_f_w + (size_t)layer * 80 * DI_;
        const float* dfw = dt_f_w + (size_t)layer * DI_ * 48;
        const float* dfb = dt_f_b + (size_t)layer * DI_;
        const float* afl = A_f_log + (size_t)layer * DI_ * 16;
        const float* df = D_f + (size_t)layer * DI_;
        const float* cbw = conv_b_w + (size_t)layer * DI_ * 4;
        const float* cbb = conv_b_b + (size_t)layer * DI_;
        const float* xbw = xproj_b_w + (size_t)layer * 80 * DI_;
        const float* dbw = dt_b_w + (size_t)layer * DI_ * 48;
        const float* dbb = dt_b_b + (size_t)layer * DI_;
        const float* abl = A_b_log + (size_t)layer * DI_ * 16;
        const float* db = D_b + (size_t)layer * DI_;
        const float* opw = out_proj_w + (size_t)layer * D_ * DI_;
        const float* nw = norm_w + (size_t)layer * D_;

        add_rms<<<M_, 256, 0, stream>>>(res, x, nw, hnb);
        gemm_mfma<<<dim3(24, 10, 1), 256, 0, stream>>>(
            hnb, hnb, D_, ipw, ipw, D_, nullptr, nullptr,
            xz, xz, nullptr, nullptr, 2 * DI_, M_, 2 * DI_, D_, 24, 0);
        conv_silu2<<<dim3((B_ * L_ * DI_ + 255) / 256, 2), 256, 0, stream>>>(
            xz, cfw, cfb, cbw, cbb, xcf, xcfb, xcb, xcbb);
        gemm_mfma<<<dim3(1, 10, 2), 256, 0, stream>>>(
            xcfb, xcbb, DI_, xfw, xbw, DI_, nullptr, nullptr,
            dblf, dblb, dblfb, dblbb, 80, M_, 80, DI_, 48, 0);
        gemm_mfma<<<dim3(12, 10, 2), 256, 0, stream>>>(
            dblfb, dblbb, 80, dfw, dbw, 48, dfb, dbb,
            dtf, dtb, nullptr, nullptr, DI_, M_, DI_, 48, 2, 2);
        ssm_scan2<<<dim3(384, 2), 256, 0, stream>>>(
            xcf, dtf, dblf, xcb, dtb, dblb, xz, afl, df, abl, db, yfb, ybb);
        gemm_mfma_avg<<<dim3(6, 10), 256, 0, stream>>>(
            yfb, ybb, DI_, opw, DI_, x, D_, M_, D_, DI_, 48);
    }

    // --- head ---
    final_rms<<<B_, 256, 0, stream>>>(res, x, norm_f_w, clsv);
    gemm_bt<<<dim3(16, 1), 256, 0, stream>>>(clsv, D_, head_w, D_, head_b,
                                             (float*)d_out, 1000, B_, 1000, D_, 1);
}